// Round 10
// baseline (567.142 us; speedup 1.0000x reference)
//
#include <hip/hip_runtime.h>
#include <math.h>

#define NVOX   (160*160*160)
#define PVOX   (160*160*5)        // packed u32 words per binary volume
#define ZCHUNK 10
#define NZC    16
#define FINF   INFINITY

typedef unsigned int u32;
typedef _Float16 half_t;
typedef __attribute__((ext_vector_type(8))) _Float16 h8;

__device__ __forceinline__ float min3(float a, float b, float c) { return fminf(a, fminf(b, c)); }
__device__ __forceinline__ float max3(float a, float b, float c) { return fmaxf(a, fmaxf(b, c)); }
__device__ __forceinline__ float sigd(float d) { return 1.0f / (1.0f + __expf(d)); }  // d = x0-x1

__device__ __forceinline__ void ld8f(const float* p, float* o) {
    float4 a = *(const float4*)p; float4 b = *(const float4*)(p + 4);
    o[0]=a.x; o[1]=a.y; o[2]=a.z; o[3]=a.w; o[4]=b.x; o[5]=b.y; o[6]=b.z; o[7]=b.w;
}
__device__ __forceinline__ void st8f(float* p, const float* o) {
    *(float4*)p       = make_float4(o[0], o[1], o[2], o[3]);
    *(float4*)(p + 4) = make_float4(o[4], o[5], o[6], o[7]);
}
__device__ __forceinline__ void ld8h(const half_t* p, float* o) {
    h8 v = *(const h8*)p;
#pragma unroll
    for (int k = 0; k < 8; ++k) o[k] = (float)v[k];
}
__device__ __forceinline__ void st8h(half_t* p, const float* o) {
    h8 v;
#pragma unroll
    for (int k = 0; k < 8; ++k) v[k] = (half_t)o[k];
    *(h8*)p = v;
}
__device__ __forceinline__ void ld8sig(const float* p0, const float* p1, float* o) {
    float a0[8], a1[8]; ld8f(p0, a0); ld8f(p1, a1);
#pragma unroll
    for (int k = 0; k < 8; ++k) o[k] = sigd(a0[k] - a1[k]);
}

// ---------------------------------------------------------------------------
// One skeletonization iteration, TWO z-planes per loop step (1 barrier/plane).
// fg (fp16 continuous, blockIdx.z 0..1) and tg (bit-packed binary, z 2..3).
// Pipeline state entering step zo: xA=x(zo), xB=x(zo+1), Ah0/1=A(zo),A(zo+1),
// Bh0/1=B(zo-1),B(zo), mh0=m(zo). Step computes A(zo+2),A(zo+3),
// m(zo+1),m(zo+2), B(zo+1),B(zo+2); emits planes zo and zo+1.
// SRC: 1 = derive from inputs (sigmoid / pack target + snapshot pO)
// SINK:1 = accumulate sums (fg: sum(skel), sum(skel*tgO); tg: popcount)
// ---------------------------------------------------------------------------
template<int SRC, int SINK>
__global__ __launch_bounds__(256, 4) void sweep(
        const half_t* __restrict__ src, half_t* __restrict__ dst,
        const u32* __restrict__ psrc, u32* __restrict__ pdst,
        const float* __restrict__ net, const int* __restrict__ tgt,
        u32* __restrict__ porig, float* __restrict__ acc)
{
    __shared__ float rmbuf[2][12][172];
    __shared__ float bmx[2][10][172];
    __shared__ u32   rmT[2][12][8];
    __shared__ u32   bmT[2][10][8];
    __shared__ float red[2][4];

    const int vol  = blockIdx.z;
    const int Y0   = blockIdx.x * 8;
    const int zbeg = blockIdx.y * ZCHUNK;
    const int zend = zbeg + ZCHUNK;
    const int lane = threadIdx.x & 63;
    const int wv   = threadIdx.x >> 6;
    const int r3   = lane / 20;
    const int xt   = lane - r3 * 20;
    const int R    = wv * 3 + r3;
    const bool act = (r3 < 3);
    const int gy1  = (R == 11) ? (Y0 - 2) : (Y0 - 1 + R);
    const int ri   = gy1 - (Y0 - 2);
    const int gym  = Y0 - 1 + R;
    const bool mrow = act && (R < 10);
    const bool orow = act && (R >= 1) && (R <= 8);

    if (vol >= 2) {
        // ================= tg path: packed binary morphology ================
        const int b = vol - 2;
        const u32* sv = psrc + (size_t)b * PVOX;
        u32*       dv = pdst + (size_t)b * PVOX;
        const bool wok = act && (xt < 5);
        const bool gok = wok && ((unsigned)gy1 < 160u);

        u32 xA = 0, xB = 0, Ah0 = ~0u, Ah1 = ~0u, Bh0 = 0, Bh1 = 0, mh0 = 0;
        unsigned int cnt = 0;

        for (int zo = zbeg - 4; zo < zend; zo += 2) {
            const int zl0 = zo + 2, zl1 = zo + 3;
            // stage 1: load/pack 2 words, rowmin-x (AND) -> rmT
            u32 w0 = ~0u, w1 = ~0u;
            if (gok) {
                if (SRC == 0) {
                    if ((unsigned)zl0 < 160u) w0 = sv[((size_t)zl0 * 160 + gy1) * 5 + xt];
                    if ((unsigned)zl1 < 160u) w1 = sv[((size_t)zl1 * 160 + gy1) * 5 + xt];
                } else {
#pragma unroll
                    for (int pl = 0; pl < 2; ++pl) {
                        const int zl = zl0 + pl;
                        if ((unsigned)zl >= 160u) continue;
                        u32 w = 0;
                        const int* tp = tgt + (size_t)b * NVOX + ((size_t)zl * 160 + gy1) * 160 + xt * 32;
#pragma unroll
                        for (int q = 0; q < 8; ++q) {
                            int4 t4 = ((const int4*)tp)[q];
                            w |= (t4.x == 1 ? 1u : 0u) << (q * 4 + 0);
                            w |= (t4.y == 1 ? 1u : 0u) << (q * 4 + 1);
                            w |= (t4.z == 1 ? 1u : 0u) << (q * 4 + 2);
                            w |= (t4.w == 1 ? 1u : 0u) << (q * 4 + 3);
                        }
                        porig[(size_t)b * PVOX + ((size_t)zl * 160 + gy1) * 5 + xt] = w;
                        if (pl == 0) w0 = w; else w1 = w;
                    }
                }
            }
            u32 pw0 = __shfl(w0, lane - 1); if (xt == 0) pw0 = ~0u;
            u32 nw0 = __shfl(w0, lane + 1); if (xt == 4) nw0 = ~0u;
            u32 pw1 = __shfl(w1, lane - 1); if (xt == 0) pw1 = ~0u;
            u32 nw1 = __shfl(w1, lane + 1); if (xt == 4) nw1 = ~0u;
            if (wok) {
                rmT[0][ri][xt] = ((w0 << 1) | (pw0 >> 31)) & w0 & ((w0 >> 1) | (nw0 << 31));
                rmT[1][ri][xt] = ((w1 << 1) | (pw1 >> 31)) & w1 & ((w1 >> 1) | (nw1 << 31));
            }
            __syncthreads();

            // stage 2: colmin (AND) -> A, m = z-AND, rowmax (OR) -> bmT
            u32 m0 = 0, m1 = 0;
            if (mrow && xt < 5) {
                const u32 A0 = rmT[0][R][xt] & rmT[0][R + 1][xt] & rmT[0][R + 2][xt];
                const u32 A1 = rmT[1][R][xt] & rmT[1][R + 1][xt] & rmT[1][R + 2][xt];
                m0 = Ah0 & Ah1 & A0;
                m1 = Ah1 & A0 & A1;
                Ah0 = A0; Ah1 = A1;
                const bool gv = (unsigned)gym < 160u;
                if (!((unsigned)(zo + 1) < 160u && gv)) m0 = 0;
                if (!((unsigned)(zo + 2) < 160u && gv)) m1 = 0;
            }
            u32 pm0 = __shfl(m0, lane - 1); if (xt == 0) pm0 = 0;
            u32 nm0 = __shfl(m0, lane + 1); if (xt == 4) nm0 = 0;
            u32 pm1 = __shfl(m1, lane - 1); if (xt == 0) pm1 = 0;
            u32 nm1 = __shfl(m1, lane + 1); if (xt == 4) nm1 = 0;
            if (mrow && xt < 5) {
                bmT[0][R][xt] = ((m0 << 1) | (pm0 >> 31)) | m0 | ((m0 >> 1) | (nm0 << 31));
                bmT[1][R][xt] = ((m1 << 1) | (pm1 >> 31)) | m1 | ((m1 >> 1) | (nm1 << 31));
            }
            __syncthreads();

            // stage 4: colmax (OR) -> B(zo+1), B(zo+2); emit planes zo, zo+1
            if (orow && xt < 5) {
                const u32 B0 = bmT[0][R - 1][xt] | bmT[0][R][xt] | bmT[0][R + 1][xt];
                const u32 B1 = bmT[1][R - 1][xt] | bmT[1][R][xt] | bmT[1][R + 1][xt];
                if (zo >= zbeg) {
                    const u32 xo0 = xA & ~((Bh0 | Bh1 | B0) & ~mh0);
                    const u32 xo1 = xB & ~((Bh1 | B0 | B1) & ~m0);
                    dv[((size_t)zo * 160 + gym) * 5 + xt]       = xo0;
                    dv[((size_t)(zo + 1) * 160 + gym) * 5 + xt] = xo1;
                    if (SINK == 1) cnt += __popc(xo0) + __popc(xo1);
                }
                Bh0 = B0; Bh1 = B1;
            }
            mh0 = m1; xA = w0; xB = w1;
        }

        if (SINK == 1) {
            float s = (float)cnt;
#pragma unroll
            for (int off = 32; off > 0; off >>= 1) s += __shfl_down(s, off);
            if (lane == 0) red[0][wv] = s;
            __syncthreads();
            if (threadIdx.x == 0)
                atomicAdd(&acc[b * 4 + 2], red[0][0] + red[0][1] + red[0][2] + red[0][3]);
        }
        return;
    }

    // ==================== fg path: fp16 continuous sweep ====================
    const int b  = vol;
    const int x0 = xt * 8;
    const half_t* sv = src + (size_t)b * NVOX;
    half_t*       dv = dst + (size_t)b * NVOX;
    const bool gok = act && ((unsigned)gy1 < 160u);

    float xA[8], xB[8], Ah0[8], Ah1[8], Bh0[8], Bh1[8], mh0[8];
#pragma unroll
    for (int k = 0; k < 8; ++k) {
        Ah0[k] = FINF; Ah1[k] = FINF; Bh0[k] = -FINF; Bh1[k] = -FINF;
        xA[k] = 0.f; xB[k] = 0.f; mh0[k] = 0.f;
    }
    float s0 = 0.f, s1 = 0.f;

    for (int zo = zbeg - 4; zo < zend; zo += 2) {
        const int zl0 = zo + 2, zl1 = zo + 3;

        // stage 1: load x(zl0), x(zl1), rowmin-x -> rmbuf[0], rmbuf[1]
        float xv0[8], xv1[8];
#pragma unroll
        for (int k = 0; k < 8; ++k) { xv0[k] = FINF; xv1[k] = FINF; }
        if (gok) {
            if ((unsigned)zl0 < 160u) {
                const size_t base = ((size_t)zl0 * 160 + gy1) * 160 + x0;
                if (SRC == 0) ld8h(sv + base, xv0);
                else ld8sig(net + (size_t)(b * 2 + 0) * NVOX + base,
                            net + (size_t)(b * 2 + 1) * NVOX + base, xv0);
            }
            if ((unsigned)zl1 < 160u) {
                const size_t base = ((size_t)zl1 * 160 + gy1) * 160 + x0;
                if (SRC == 0) ld8h(sv + base, xv1);
                else ld8sig(net + (size_t)(b * 2 + 0) * NVOX + base,
                            net + (size_t)(b * 2 + 1) * NVOX + base, xv1);
            }
        }
        {
            float vL0 = __shfl(xv0[7], lane - 1); if (xt == 0)  vL0 = FINF;
            float vR0 = __shfl(xv0[0], lane + 1); if (xt == 19) vR0 = FINF;
            float vL1 = __shfl(xv1[7], lane - 1); if (xt == 0)  vL1 = FINF;
            float vR1 = __shfl(xv1[0], lane + 1); if (xt == 19) vR1 = FINF;
            float r0[8], r1[8];
            r0[0] = min3(vL0, xv0[0], xv0[1]);
            r1[0] = min3(vL1, xv1[0], xv1[1]);
#pragma unroll
            for (int k = 1; k < 7; ++k) {
                r0[k] = min3(xv0[k-1], xv0[k], xv0[k+1]);
                r1[k] = min3(xv1[k-1], xv1[k], xv1[k+1]);
            }
            r0[7] = min3(xv0[6], xv0[7], vR0);
            r1[7] = min3(xv1[6], xv1[7], vR1);
            if (act) { st8f(&rmbuf[0][ri][x0], r0); st8f(&rmbuf[1][ri][x0], r1); }
        }
        __syncthreads();

        // stage 2: colmin -> A(zl0),A(zl1); m(zo+1),m(zo+2); rowmax -> bmx
        float m0_[8], m1_[8];
        if (mrow) {
            float p0[8], p1[8], p2[8], q0[8], q1[8], q2[8];
            ld8f(&rmbuf[0][R][x0], p0); ld8f(&rmbuf[0][R+1][x0], p1); ld8f(&rmbuf[0][R+2][x0], p2);
            ld8f(&rmbuf[1][R][x0], q0); ld8f(&rmbuf[1][R+1][x0], q1); ld8f(&rmbuf[1][R+2][x0], q2);
            const bool gv  = (unsigned)gym < 160u;
            const bool mv0 = ((unsigned)(zo + 1) < 160u) && gv;
            const bool mv1 = ((unsigned)(zo + 2) < 160u) && gv;
#pragma unroll
            for (int k = 0; k < 8; ++k) {
                const float A0 = min3(p0[k], p1[k], p2[k]);
                const float A1 = min3(q0[k], q1[k], q2[k]);
                const float m0 = min3(Ah0[k], Ah1[k], A0);
                const float m1 = min3(Ah1[k], A0, A1);
                Ah0[k] = A0; Ah1[k] = A1;
                m0_[k] = mv0 ? m0 : -FINF;
                m1_[k] = mv1 ? m1 : -FINF;
            }
        } else {
#pragma unroll
            for (int k = 0; k < 8; ++k) { m0_[k] = -FINF; m1_[k] = -FINF; }
        }
        {
            float mL0 = __shfl(m0_[7], lane - 1); if (xt == 0)  mL0 = -FINF;
            float mR0 = __shfl(m0_[0], lane + 1); if (xt == 19) mR0 = -FINF;
            float mL1 = __shfl(m1_[7], lane - 1); if (xt == 0)  mL1 = -FINF;
            float mR1 = __shfl(m1_[0], lane + 1); if (xt == 19) mR1 = -FINF;
            if (mrow) {
                float b0[8], b1[8];
                b0[0] = max3(mL0, m0_[0], m0_[1]);
                b1[0] = max3(mL1, m1_[0], m1_[1]);
#pragma unroll
                for (int k = 1; k < 7; ++k) {
                    b0[k] = max3(m0_[k-1], m0_[k], m0_[k+1]);
                    b1[k] = max3(m1_[k-1], m1_[k], m1_[k+1]);
                }
                b0[7] = max3(m0_[6], m0_[7], mR0);
                b1[7] = max3(m1_[6], m1_[7], mR1);
                st8f(&bmx[0][R][x0], b0); st8f(&bmx[1][R][x0], b1);
            }
        }
        __syncthreads();

        // stage 4: colmax -> B(zo+1),B(zo+2); emit planes zo, zo+1
        if (orow) {
            float a0[8], a1[8], a2[8], c0[8], c1[8], c2[8], Bn0[8], Bn1[8];
            ld8f(&bmx[0][R-1][x0], a0); ld8f(&bmx[0][R][x0], a1); ld8f(&bmx[0][R+1][x0], a2);
            ld8f(&bmx[1][R-1][x0], c0); ld8f(&bmx[1][R][x0], c1); ld8f(&bmx[1][R+1][x0], c2);
#pragma unroll
            for (int k = 0; k < 8; ++k) {
                Bn0[k] = max3(a0[k], a1[k], a2[k]);
                Bn1[k] = max3(c0[k], c1[k], c2[k]);
            }
            if (zo >= zbeg) {
                float o0[8], o1[8];
#pragma unroll
                for (int k = 0; k < 8; ++k) {
                    const float ct0 = fmaxf(max3(Bh0[k], Bh1[k], Bn0[k]) - mh0[k], 0.f);
                    const float ct1 = fmaxf(max3(Bh1[k], Bn0[k], Bn1[k]) - m0_[k], 0.f);
                    o0[k] = fmaxf(xA[k] - ct0, 0.f);
                    o1[k] = fmaxf(xB[k] - ct1, 0.f);
                }
                const size_t ob0 = ((size_t)zo * 160 + gym) * 160 + x0;
                const size_t ob1 = ((size_t)(zo + 1) * 160 + gym) * 160 + x0;
                if (SINK == 0) {
                    st8h(dv + ob0, o0);
                    st8h(dv + ob1, o1);
                } else {
                    const u32 w0 = porig[(size_t)b * PVOX + ((size_t)zo * 160 + gym) * 5 + (x0 >> 5)];
                    const u32 w1 = porig[(size_t)b * PVOX + ((size_t)(zo + 1) * 160 + gym) * 5 + (x0 >> 5)];
                    const int sh = x0 & 31;
#pragma unroll
                    for (int k = 0; k < 8; ++k) {
                        s0 += o0[k] + o1[k];
                        s1 += (((w0 >> (sh + k)) & 1u) ? o0[k] : 0.f)
                            + (((w1 >> (sh + k)) & 1u) ? o1[k] : 0.f);
                    }
                }
            }
#pragma unroll
            for (int k = 0; k < 8; ++k) { Bh0[k] = Bn0[k]; Bh1[k] = Bn1[k]; }
        }
#pragma unroll
        for (int k = 0; k < 8; ++k) {
            mh0[k] = m1_[k];
            xA[k] = xv0[k]; xB[k] = xv1[k];
        }
    }

    if (SINK == 1) {
#pragma unroll
        for (int off = 32; off > 0; off >>= 1) {
            s0 += __shfl_down(s0, off);
            s1 += __shfl_down(s1, off);
        }
        if (lane == 0) { red[0][wv] = s0; red[1][wv] = s1; }
        __syncthreads();
        if (threadIdx.x == 0) {
            atomicAdd(&acc[b * 4 + 0], red[0][0] + red[0][1] + red[0][2] + red[0][3]);
            atomicAdd(&acc[b * 4 + 1], red[1][0] + red[1][1] + red[1][2] + red[1][3]);
        }
    }
}

// sum(skel_tg * fg_orig): stream net once, gate by packed final-tg bits
__global__ __launch_bounds__(256) void reduce_tf(const float* __restrict__ net,
                                                 const u32* __restrict__ pfin,
                                                 float* __restrict__ acc) {
    const int b = blockIdx.y;
    const float* n0 = net + (size_t)(b * 2 + 0) * NVOX;
    const float* n1 = net + (size_t)(b * 2 + 1) * NVOX;
    const u32*   pf = pfin + (size_t)b * PVOX;
    float s = 0.f;
    for (int i = (blockIdx.x * 256 + threadIdx.x) * 8; i < NVOX; i += gridDim.x * 256 * 8) {
        const u32 byte = (pf[i >> 5] >> (i & 31)) & 0xffu;
        if (byte) {
            float a0[8], a1[8];
            ld8f(n0 + i, a0); ld8f(n1 + i, a1);
#pragma unroll
            for (int k = 0; k < 8; ++k)
                if ((byte >> k) & 1u) s += sigd(a0[k] - a1[k]);
        }
    }
#pragma unroll
    for (int off = 32; off > 0; off >>= 1) s += __shfl_down(s, off);
    __shared__ float part[4];
    const int wv = threadIdx.x >> 6, lane = threadIdx.x & 63;
    if (lane == 0) part[wv] = s;
    __syncthreads();
    if (threadIdx.x == 0) atomicAdd(&acc[b * 4 + 3], part[0] + part[1] + part[2] + part[3]);
}

__global__ void zero_acc(float* acc) {
    if (threadIdx.x < 8) acc[threadIdx.x] = 0.f;
}

__global__ void finalize(const float* __restrict__ acc, float* __restrict__ out) {
    if (threadIdx.x == 0) {
        const float i0 = (acc[1] + 1.f) / (acc[0] + 1.f);
        const float t0 = (acc[3] + 1.f) / (acc[2] + 1.f);
        const float i1 = (acc[5] + 1.f) / (acc[4] + 1.f);
        const float t1 = (acc[7] + 1.f) / (acc[6] + 1.f);
        const float inter = i0 * t0 + i1 * t1;
        out[0] = -(2.f * inter / ((i0 + i1) + (t0 + t1)));
    }
}

// ---------------------------------------------------------------------------
extern "C" void kernel_launch(void* const* d_in, const int* in_sizes, int n_in,
                              void* d_out, int out_size, void* d_ws, size_t ws_size,
                              hipStream_t stream) {
    const float* net = (const float*)d_in[0];   // (2,2,160,160,160) f32
    const int*   tgt = (const int*)d_in[1];     // (2,1,160,160,160) int32
    half_t* bufA = (half_t*)d_ws;               // 2 fp16 volumes
    half_t* bufB = bufA + (size_t)2 * NVOX;
    u32* pA = (u32*)(bufB + (size_t)2 * NVOX);  // 2 packed volumes
    u32* pB = pA + (size_t)2 * PVOX;
    u32* pO = pB + (size_t)2 * PVOX;            // packed original target
    float* acc = (float*)(pO + (size_t)2 * PVOX);

    zero_acc<<<1, 64, 0, stream>>>(acc);

    const dim3 grid(20, NZC, 4);                // y-tiles x z-chunks x (2 fg + 2 tg)
    sweep<1, 0><<<grid, 256, 0, stream>>>(bufB, bufA, pB, pA, net, tgt, pO, acc);
    half_t* s = bufA; half_t* d = bufB;
    u32* ps = pA; u32* pd = pB;
    for (int it = 1; it <= 8; ++it) {
        sweep<0, 0><<<grid, 256, 0, stream>>>(s, d, ps, pd, net, tgt, pO, acc);
        half_t* t = s; s = d; d = t;
        u32* q = ps; ps = pd; pd = q;
    }
    sweep<0, 1><<<grid, 256, 0, stream>>>(s, d, ps, pd, net, tgt, pO, acc);

    reduce_tf<<<dim3(512, 2), 256, 0, stream>>>(net, pd, acc);
    finalize<<<1, 64, 0, stream>>>(acc, (float*)d_out);
}

// Round 11
// 379.753 us; speedup vs baseline: 1.4934x; 1.4934x over previous
//
#include <hip/hip_runtime.h>
#include <math.h>

#define NVOX   (160*160*160)
#define PVOX   (160*160*5)        // packed u32 words per binary volume
#define ZCHUNK 10
#define NZC    16
#define FINF   INFINITY

typedef unsigned int u32;
typedef _Float16 half_t;
typedef __attribute__((ext_vector_type(8))) _Float16 h8;

__device__ __forceinline__ float min3(float a, float b, float c) { return fminf(a, fminf(b, c)); }
__device__ __forceinline__ float max3(float a, float b, float c) { return fmaxf(a, fmaxf(b, c)); }
__device__ __forceinline__ float sigd(float d) { return 1.0f / (1.0f + __expf(d)); }  // d = x0-x1

__device__ __forceinline__ void ld8f(const float* p, float* o) {
    float4 a = *(const float4*)p; float4 b = *(const float4*)(p + 4);
    o[0]=a.x; o[1]=a.y; o[2]=a.z; o[3]=a.w; o[4]=b.x; o[5]=b.y; o[6]=b.z; o[7]=b.w;
}
__device__ __forceinline__ void st8f(float* p, const float* o) {
    *(float4*)p       = make_float4(o[0], o[1], o[2], o[3]);
    *(float4*)(p + 4) = make_float4(o[4], o[5], o[6], o[7]);
}
__device__ __forceinline__ void ld8h(const half_t* p, float* o) {
    h8 v = *(const h8*)p;
#pragma unroll
    for (int k = 0; k < 8; ++k) o[k] = (float)v[k];
}
__device__ __forceinline__ void st8h(half_t* p, const float* o) {
    h8 v;
#pragma unroll
    for (int k = 0; k < 8; ++k) v[k] = (half_t)o[k];
    *(h8*)p = v;
}

// Raw barrier that orders LDS (lgkmcnt(0)) but does NOT drain vmcnt —
// keeps the prefetched global loads in flight across the barrier
// (hipcc's __syncthreads emits s_waitcnt vmcnt(0) which would defeat it).
// No intra-kernel cross-wave communication goes through global memory,
// so skipping the vmcnt drain is safe.
__device__ __forceinline__ void lds_barrier() {
    asm volatile("s_waitcnt lgkmcnt(0)" ::: "memory");
    __builtin_amdgcn_s_barrier();
    __builtin_amdgcn_sched_barrier(0);
}

// ---------------------------------------------------------------------------
// One skeletonization iteration (1 z-plane/step, R8-verified pipeline) with
// register prefetch of the next x-plane across raw barriers.
// fg (fp16, blockIdx.z 0..1) / tg (bit-packed, z 2..3).
// Pipeline at step zo: xv=x(zo+2) consumed; stage4 reads xh1 = x(zo).
// SRC: 1 = derive from inputs (sigmoid->also snapshot forig / pack tgt->pO)
// SINK:1 = accumulate sums (fg: sum(skel), sum(skel*tgO); tg: popcount)
// ---------------------------------------------------------------------------
template<int SRC, int SINK>
__global__ __launch_bounds__(256) void sweep(
        const half_t* __restrict__ src, half_t* __restrict__ dst,
        const u32* __restrict__ psrc, u32* __restrict__ pdst,
        const float* __restrict__ net, const int* __restrict__ tgt,
        u32* __restrict__ porig, half_t* __restrict__ forig,
        float* __restrict__ acc)
{
    __shared__ float rmbuf[12][172];
    __shared__ float bmx[10][172];
    __shared__ u32   rmT[12][8];
    __shared__ u32   bmT[10][8];
    __shared__ float red[2][4];

    const int vol  = blockIdx.z;
    const int Y0   = blockIdx.x * 8;
    const int zbeg = blockIdx.y * ZCHUNK;
    const int zend = zbeg + ZCHUNK;
    const int lane = threadIdx.x & 63;
    const int wv   = threadIdx.x >> 6;
    const int r3   = lane / 20;
    const int xt   = lane - r3 * 20;
    const int R    = wv * 3 + r3;
    const bool act = (r3 < 3);
    const int gy1  = (R == 11) ? (Y0 - 2) : (Y0 - 1 + R);
    const int ri   = gy1 - (Y0 - 2);
    const int gym  = Y0 - 1 + R;
    const bool mrow = act && (R < 10);
    const bool orow = act && (R >= 1) && (R <= 8);

    if (vol >= 2) {
        // ================= tg path: packed binary morphology ================
        const int b = vol - 2;
        const u32* sv = psrc + (size_t)b * PVOX;
        u32*       dv = pdst + (size_t)b * PVOX;
        const bool wok = act && (xt < 5);
        const bool gok = wok && ((unsigned)gy1 < 160u);

        u32 xh1 = 0, xh2 = 0, Ah0 = ~0u, Ah1 = ~0u, Bh0 = 0, Bh1 = 0, mh0 = 0;
        unsigned int cnt = 0;

        u32 pf_w = ~0u; bool pf_v = false;
        if (SRC == 0) {                     // prologue prefetch, zl = zbeg-2
            const int zl = zbeg - 2;
            pf_v = gok && ((unsigned)zl < 160u);
            if (pf_v) pf_w = sv[((size_t)zl * 160 + gy1) * 5 + xt];
        }

        for (int zo = zbeg - 4; zo < zend; ++zo) {
            const int zl = zo + 2, zm = zo + 1;
            // stage 1: consume prefetched word / pack, rowmin-x (AND) -> rmT
            u32 w = ~0u;
            if (SRC == 0) {
                w = pf_v ? pf_w : ~0u;
            } else if (gok && (unsigned)zl < 160u) {
                w = 0;
                const int* tp = tgt + (size_t)b * NVOX + ((size_t)zl * 160 + gy1) * 160 + xt * 32;
#pragma unroll
                for (int q = 0; q < 8; ++q) {
                    int4 t4 = ((const int4*)tp)[q];
                    w |= (t4.x == 1 ? 1u : 0u) << (q * 4 + 0);
                    w |= (t4.y == 1 ? 1u : 0u) << (q * 4 + 1);
                    w |= (t4.z == 1 ? 1u : 0u) << (q * 4 + 2);
                    w |= (t4.w == 1 ? 1u : 0u) << (q * 4 + 3);
                }
                porig[(size_t)b * PVOX + ((size_t)zl * 160 + gy1) * 5 + xt] = w;
            }
            u32 pwd = __shfl(w, lane - 1); if (xt == 0) pwd = ~0u;
            u32 nwd = __shfl(w, lane + 1); if (xt == 4) nwd = ~0u;
            if (wok) rmT[ri][xt] = ((w << 1) | (pwd >> 31)) & w & ((w >> 1) | (nwd << 31));
            if (SRC == 0) {                 // prefetch next plane
                const int zln = zl + 1;
                pf_v = gok && ((unsigned)zln < 160u);
                if (pf_v) pf_w = sv[((size_t)zln * 160 + gy1) * 5 + xt];
            }
            lds_barrier();

            // stage 2: colmin (AND) -> A, m = z-AND, rowmax (OR) -> bmT
            u32 m = 0;
            if (mrow && xt < 5) {
                const u32 A = rmT[R][xt] & rmT[R + 1][xt] & rmT[R + 2][xt];
                m = A & Ah0 & Ah1;
                Ah0 = Ah1; Ah1 = A;
                if (!((unsigned)zm < 160u && (unsigned)gym < 160u)) m = 0;
            }
            u32 pmd = __shfl(m, lane - 1); if (xt == 0) pmd = 0;
            u32 nmd = __shfl(m, lane + 1); if (xt == 4) nmd = 0;
            if (mrow && xt < 5)
                bmT[R][xt] = ((m << 1) | (pmd >> 31)) | m | ((m >> 1) | (nmd << 31));
            lds_barrier();

            // stage 4: colmax (OR) -> B, emit plane zo
            if (orow && xt < 5) {
                const u32 B = bmT[R - 1][xt] | bmT[R][xt] | bmT[R + 1][xt];
                if (zo >= zbeg) {
                    const u32 cm = B | Bh0 | Bh1;
                    const u32 xo = xh1 & ~(cm & ~mh0);
                    dv[((size_t)zo * 160 + gym) * 5 + xt] = xo;
                    if (SINK == 1) cnt += __popc(xo);
                }
                Bh0 = Bh1; Bh1 = B;
            }
            mh0 = m; xh1 = xh2; xh2 = w;
        }

        if (SINK == 1) {
            float s = (float)cnt;
#pragma unroll
            for (int off = 32; off > 0; off >>= 1) s += __shfl_down(s, off);
            if (lane == 0) red[0][wv] = s;
            __syncthreads();
            if (threadIdx.x == 0)
                atomicAdd(&acc[b * 4 + 2], red[0][0] + red[0][1] + red[0][2] + red[0][3]);
        }
        return;
    }

    // ==================== fg path: fp16 continuous sweep ====================
    const int b  = vol;
    const int x0 = xt * 8;
    const half_t* sv = src + (size_t)b * NVOX;
    half_t*       dv = dst + (size_t)b * NVOX;
    const bool gok = act && ((unsigned)gy1 < 160u);

    float xh1[8], xh2[8], Ah0[8], Ah1[8], Bh0[8], Bh1[8], mh0[8];
#pragma unroll
    for (int k = 0; k < 8; ++k) {
        Ah0[k] = FINF; Ah1[k] = FINF; Bh0[k] = -FINF; Bh1[k] = -FINF;
        xh1[k] = 0.f; xh2[k] = 0.f; mh0[k] = 0.f;
    }
    float s0 = 0.f, s1 = 0.f;

    float nA[8], nB[8];     // prefetched raw data for the next x-plane
    bool  nval = false;

    auto issue = [&](int zl) {              // issue loads only, no dependent math
        nval = gok && ((unsigned)zl < 160u);
        if (nval) {
            const size_t base = ((size_t)zl * 160 + gy1) * 160 + x0;
            if (SRC == 0) {
                ld8h(sv + base, nA);
            } else {
                ld8f(net + (size_t)(b * 2 + 0) * NVOX + base, nA);
                ld8f(net + (size_t)(b * 2 + 1) * NVOX + base, nB);
            }
        }
    };

    issue(zbeg - 2);                        // prologue prefetch

    for (int zo = zbeg - 4; zo < zend; ++zo) {
        const int zl = zo + 2, zm = zo + 1;

        // stage 1: consume prefetched plane, rowmin-x -> rmbuf
        float xv[8];
        if (nval) {
            if (SRC == 0) {
#pragma unroll
                for (int k = 0; k < 8; ++k) xv[k] = nA[k];
            } else {
#pragma unroll
                for (int k = 0; k < 8; ++k) xv[k] = sigd(nA[k] - nB[k]);
                st8h(forig + (size_t)b * NVOX + ((size_t)zl * 160 + gy1) * 160 + x0, xv);
            }
        } else {
#pragma unroll
            for (int k = 0; k < 8; ++k) xv[k] = FINF;
        }
        {
            float vL = __shfl(xv[7], lane - 1); if (xt == 0)  vL = FINF;
            float vR = __shfl(xv[0], lane + 1); if (xt == 19) vR = FINF;
            float r[8];
            r[0] = min3(vL, xv[0], xv[1]);
#pragma unroll
            for (int k = 1; k < 7; ++k) r[k] = min3(xv[k-1], xv[k], xv[k+1]);
            r[7] = min3(xv[6], xv[7], vR);
            if (act) st8f(&rmbuf[ri][x0], r);
        }
        issue(zl + 1);                      // prefetch next plane (in flight across barriers)
        lds_barrier();

        // stage 2: colmin->A, m = z-min, rowmax->bmx
        float m_[8];
        if (mrow) {
            float p0[8], p1[8], p2[8];
            ld8f(&rmbuf[R][x0], p0); ld8f(&rmbuf[R+1][x0], p1); ld8f(&rmbuf[R+2][x0], p2);
            const bool mv = ((unsigned)zm < 160u) && ((unsigned)gym < 160u);
#pragma unroll
            for (int k = 0; k < 8; ++k) {
                const float An = min3(p0[k], p1[k], p2[k]);
                float m = min3(An, Ah0[k], Ah1[k]);
                Ah0[k] = Ah1[k]; Ah1[k] = An;
                m_[k] = mv ? m : -FINF;
            }
        } else {
#pragma unroll
            for (int k = 0; k < 8; ++k) m_[k] = -FINF;
        }
        {
            float mL = __shfl(m_[7], lane - 1); if (xt == 0)  mL = -FINF;
            float mR = __shfl(m_[0], lane + 1); if (xt == 19) mR = -FINF;
            if (mrow) {
                float bm[8];
                bm[0] = max3(mL, m_[0], m_[1]);
#pragma unroll
                for (int k = 1; k < 7; ++k) bm[k] = max3(m_[k-1], m_[k], m_[k+1]);
                bm[7] = max3(m_[6], m_[7], mR);
                st8f(&bmx[R][x0], bm);
            }
        }
        lds_barrier();

        // stage 4: colmax->B(zm), emit plane zo (x(zo) lives in xh1)
        if (orow) {
            float q0[8], q1[8], q2[8], Bn[8];
            ld8f(&bmx[R-1][x0], q0); ld8f(&bmx[R][x0], q1); ld8f(&bmx[R+1][x0], q2);
#pragma unroll
            for (int k = 0; k < 8; ++k) Bn[k] = max3(q0[k], q1[k], q2[k]);
            if (zo >= zbeg) {
                float o[8];
#pragma unroll
                for (int k = 0; k < 8; ++k) {
                    const float cm = max3(Bn[k], Bh0[k], Bh1[k]);
                    const float ct = fmaxf(cm - mh0[k], 0.f);
                    o[k] = fmaxf(xh1[k] - ct, 0.f);
                }
                const size_t ob = ((size_t)zo * 160 + gym) * 160 + x0;
                if (SINK == 0) {
                    st8h(dv + ob, o);
                } else {
                    const u32 w = porig[(size_t)b * PVOX + ((size_t)zo * 160 + gym) * 5 + (x0 >> 5)];
                    const int sh = x0 & 31;
#pragma unroll
                    for (int k = 0; k < 8; ++k) {
                        s0 += o[k];
                        s1 += ((w >> (sh + k)) & 1u) ? o[k] : 0.f;
                    }
                }
            }
#pragma unroll
            for (int k = 0; k < 8; ++k) { Bh0[k] = Bh1[k]; Bh1[k] = Bn[k]; }
        }
#pragma unroll
        for (int k = 0; k < 8; ++k) {
            mh0[k] = m_[k];
            xh1[k] = xh2[k]; xh2[k] = xv[k];
        }
    }

    if (SINK == 1) {
#pragma unroll
        for (int off = 32; off > 0; off >>= 1) {
            s0 += __shfl_down(s0, off);
            s1 += __shfl_down(s1, off);
        }
        if (lane == 0) { red[0][wv] = s0; red[1][wv] = s1; }
        __syncthreads();
        if (threadIdx.x == 0) {
            atomicAdd(&acc[b * 4 + 0], red[0][0] + red[0][1] + red[0][2] + red[0][3]);
            atomicAdd(&acc[b * 4 + 1], red[1][0] + red[1][1] + red[1][2] + red[1][3]);
        }
    }
}

// sum(skel_tg * fg_orig): read fp16 fg snapshot gated by packed final-tg bits
__global__ __launch_bounds__(256) void reduce_tf(const half_t* __restrict__ forig,
                                                 const u32* __restrict__ pfin,
                                                 float* __restrict__ acc) {
    const int b = blockIdx.y;
    const half_t* f = forig + (size_t)b * NVOX;
    const u32*   pf = pfin + (size_t)b * PVOX;
    float s = 0.f;
    for (int i = (blockIdx.x * 256 + threadIdx.x) * 8; i < NVOX; i += gridDim.x * 256 * 8) {
        const u32 byte = (pf[i >> 5] >> (i & 31)) & 0xffu;
        if (byte) {
            float a[8]; ld8h(f + i, a);
#pragma unroll
            for (int k = 0; k < 8; ++k)
                if ((byte >> k) & 1u) s += a[k];
        }
    }
#pragma unroll
    for (int off = 32; off > 0; off >>= 1) s += __shfl_down(s, off);
    __shared__ float part[4];
    const int wvi = threadIdx.x >> 6, lane = threadIdx.x & 63;
    if (lane == 0) part[wvi] = s;
    __syncthreads();
    if (threadIdx.x == 0) atomicAdd(&acc[b * 4 + 3], part[0] + part[1] + part[2] + part[3]);
}

__global__ void zero_acc(float* acc) {
    if (threadIdx.x < 8) acc[threadIdx.x] = 0.f;
}

__global__ void finalize(const float* __restrict__ acc, float* __restrict__ out) {
    if (threadIdx.x == 0) {
        const float i0 = (acc[1] + 1.f) / (acc[0] + 1.f);
        const float t0 = (acc[3] + 1.f) / (acc[2] + 1.f);
        const float i1 = (acc[5] + 1.f) / (acc[4] + 1.f);
        const float t1 = (acc[7] + 1.f) / (acc[6] + 1.f);
        const float inter = i0 * t0 + i1 * t1;
        out[0] = -(2.f * inter / ((i0 + i1) + (t0 + t1)));
    }
}

// ---------------------------------------------------------------------------
extern "C" void kernel_launch(void* const* d_in, const int* in_sizes, int n_in,
                              void* d_out, int out_size, void* d_ws, size_t ws_size,
                              hipStream_t stream) {
    const float* net = (const float*)d_in[0];   // (2,2,160,160,160) f32
    const int*   tgt = (const int*)d_in[1];     // (2,1,160,160,160) int32
    half_t* bufA = (half_t*)d_ws;               // 2 fp16 volumes
    half_t* bufB = bufA + (size_t)2 * NVOX;
    u32* pA = (u32*)(bufB + (size_t)2 * NVOX);  // 2 packed volumes
    u32* pB = pA + (size_t)2 * PVOX;
    u32* pO = pB + (size_t)2 * PVOX;            // packed original target
    half_t* forig = (half_t*)(pO + (size_t)2 * PVOX);  // fp16 fg snapshot
    float* acc = (float*)(forig + (size_t)2 * NVOX);

    zero_acc<<<1, 64, 0, stream>>>(acc);

    const dim3 grid(20, NZC, 4);                // y-tiles x z-chunks x (2 fg + 2 tg)
    sweep<1, 0><<<grid, 256, 0, stream>>>(bufB, bufA, pB, pA, net, tgt, pO, forig, acc);
    half_t* s = bufA; half_t* d = bufB;
    u32* ps = pA; u32* pd = pB;
    for (int it = 1; it <= 8; ++it) {
        sweep<0, 0><<<grid, 256, 0, stream>>>(s, d, ps, pd, net, tgt, pO, forig, acc);
        half_t* t = s; s = d; d = t;
        u32* q = ps; ps = pd; pd = q;
    }
    sweep<0, 1><<<grid, 256, 0, stream>>>(s, d, ps, pd, net, tgt, pO, forig, acc);

    reduce_tf<<<dim3(512, 2), 256, 0, stream>>>(forig, pd, acc);
    finalize<<<1, 64, 0, stream>>>(acc, (float*)d_out);
}